// Round 12
// baseline (128.523 us; speedup 1.0000x reference)
//
#include <hip/hip_runtime.h>
#include <math.h>

#define GAMMA 0.25f
constexpr int B_ = 8, Q_ = 64, N_ = 8192, K_ = 512, C_ = 256;

typedef __attribute__((ext_vector_type(8))) short bf16x8;
typedef __attribute__((ext_vector_type(4))) short short4v;
typedef __attribute__((ext_vector_type(4))) float f32x4;

static __device__ inline short f2bf(float x) {   // RNE float->bf16 bits
    union { float f; unsigned u; } v; v.f = x;
    unsigned r = (v.u + 0x7fffu + ((v.u >> 16) & 1u)) >> 16;
    return (short)r;
}
static __device__ inline float bf2f(short h) {
    union { unsigned u; float f; } v; v.u = ((unsigned)(unsigned short)h) << 16;
    return v.f;
}

// ---------------------------------------------------------------------------
// prep: emb fp32[512][64] -> bf16 embB[512][64] + e2[k]=||bf16(emb_k)||^2 in ws.
// ---------------------------------------------------------------------------
__global__ __launch_bounds__(256) void prep_kernel(const float* __restrict__ emb,
                                                   short* __restrict__ embB,
                                                   float* __restrict__ e2g)
{
    const int r = blockIdx.x * 256 + threadIdx.x;
    if (r >= K_) return;
    const float4* src = (const float4*)(emb + r * Q_);
    short4v* dst = (short4v*)(embB + r * Q_);
    float s = 0.f;
    #pragma unroll
    for (int i = 0; i < 16; ++i) {
        const float4 v = src[i];
        short4v h;
        h[0] = f2bf(v.x); h[1] = f2bf(v.y); h[2] = f2bf(v.z); h[3] = f2bf(v.w);
        dst[i] = h;
        #pragma unroll
        for (int j = 0; j < 4; ++j) { const float a = bf2f(h[j]); s = fmaf(a, a, s); }
    }
    e2g[r] = s;
}

// ---------------------------------------------------------------------------
// mega v4: R8's verified sub-block bodies, packed TWO per 512-thread block.
// R11 evidence: replay pass with 16KB HBM traffic ran the SAME 89.5us as the
// 43MB pass -> duration insensitive to memory source; VALU/MFMA/LDS all idle;
// occupancy ~4 waves/CU. Diagnosis: dependent-chain latency x too few waves.
// Fix: waves 0-3 run sub-block 2i, waves 4-7 run sub-block 2i+1 (role-uniform
// per block, same bid%3 interleave, own LDS slice per half, identical barrier
// counts). Blocks/CU pinned ~1 -> waves/CU doubles. VGPR stays ~120 (same
// body). 1536 blocks x 512 thr. Partials + reduce (R10: atomics regressed).
// ---------------------------------------------------------------------------
__global__ __launch_bounds__(512) void mega_kernel(
    const float* __restrict__ ze, const float* __restrict__ qp,
    const int* __restrict__ tgt, const short* __restrict__ embB,
    const float* __restrict__ e2g,
    float* __restrict__ cePart, float* __restrict__ vqPart)
{
    __shared__ float smemAll[9216];          // 36.9 KB: 2x VQ slice (4352) + 2x minb(256)
    const int bid  = blockIdx.x;             // 0..1535
    const int tid  = threadIdx.x;            // 0..511
    const int h    = tid >> 8;               // half 0/1
    const int htid = tid & 255;
    const int lane = htid & 63;
    const int w    = htid >> 6;              // wave within half (0..3)

    if (bid % 3 != 0) {
        // ============ CE pair (1024 blocks -> 2048 sub-blocks) ============
        const int cpair = bid - bid / 3 - 1;     // 0..1023, dense
        const int cbid  = cpair * 2 + h;         // 0..2047
        f32x4* parts = (f32x4*)smemAll + h * 32; // per-half [32]

        const int g    = lane & 7;               // item group (4 items)
        const int c0   = lane >> 3;              // class subgroup (8)

        const int base = cbid * 32;              // 32-aligned => b uniform
        const int b    = base >> 13;
        const int n0   = base & (N_ - 1);
        const float* qpb = qp + (size_t)b * C_ * N_;
        const float* qpn = qpb + n0 + g * 4;
        const int cbase  = w * 64 + c0 * 8;

        float4 v[8];
        #pragma unroll
        for (int j = 0; j < 8; ++j)
            v[j] = *(const float4*)(qpn + (size_t)(cbase + j) * N_);

        float xts[4] = {0.f, 0.f, 0.f, 0.f};
        if ((w == 0) && (lane < 8)) {
            #pragma unroll
            for (int j = 0; j < 4; ++j) {
                const int t = tgt[base + lane * 4 + j];
                xts[j] = qpb[(size_t)t * N_ + n0 + lane * 4 + j];
            }
        }

        f32x4 acc = {0.f, 0.f, 0.f, 0.f};
        #pragma unroll
        for (int j = 0; j < 8; ++j) {
            acc[0] += __expf(v[j].x); acc[1] += __expf(v[j].y);
            acc[2] += __expf(v[j].z); acc[3] += __expf(v[j].w);
        }
        #pragma unroll
        for (int r = 0; r < 4; ++r) {            // fold c0 (lane bits 3,4,5)
            acc[r] += __shfl_xor(acc[r], 8, 64);
            acc[r] += __shfl_xor(acc[r], 16, 64);
            acc[r] += __shfl_xor(acc[r], 32, 64);
        }
        if (c0 == 0) parts[w * 8 + g] = acc;
        __syncthreads();                         // barrier #1 (both halves)

        if (w == 0) {
            float loss = 0.f;
            if (lane < 8) {
                const f32x4 tot = (parts[lane] + parts[8 + lane]) +
                                  (parts[16 + lane] + parts[24 + lane]);
                #pragma unroll
                for (int j = 0; j < 4; ++j) loss += __logf(tot[j]) - xts[j];
            }
            loss += __shfl_down(loss, 4, 64);
            loss += __shfl_down(loss, 2, 64);
            loss += __shfl_down(loss, 1, 64);
            if (lane == 0) cePart[cbid] = loss;
        }
        __syncthreads();                         // barrier #2 (match VQ count)
    } else {
        // ============ VQ pair (512 blocks -> 1024 sub-blocks) ============
        const int vpair = bid / 3;               // 0..511
        const int vbid  = vpair * 2 + h;         // 0..1023
        float* smem = smemAll + h * 4352;        // per-half zeT [64][68]
        float* minb = smemAll + 8704 + h * 256;  // per-half [256]

        const int n16  = lane & 15;
        const int quad = lane >> 4;

        const int base = vbid * 64;              // 64-aligned => b uniform
        const int b    = base >> 13;
        const int n0   = base & (N_ - 1);
        const float* zb = ze + (size_t)b * Q_ * N_;

        // ---- issue ze tile loads: half-thread owns q=htid>>2, pt=htid&3 ----
        const int q  = htid >> 2;
        const int pt = htid & 3;
        const float* zq = zb + (size_t)q * N_ + n0 + pt * 4;
        float4 st[4];
        #pragma unroll
        for (int i = 0; i < 4; ++i)
            st[i] = *(const float4*)(zq + i * 16);

        // ---- issue B tiles + e2 while ze lands (reused data, cached) ----
        const short* bb = embB + (w * 128 + n16) * Q_ + quad * 8;
        bf16x8 Bv[8][2];
        float  e2v[8];
        #pragma unroll
        for (int t = 0; t < 8; ++t) {
            Bv[t][0] = *(const bf16x8*)(bb + t * 16 * Q_);
            Bv[t][1] = *(const bf16x8*)(bb + t * 16 * Q_ + 32);
            e2v[t]   = e2g[w * 128 + t * 16 + n16];
        }

        // ---- write ze to LDS transposed [n][q] ----
        #pragma unroll
        for (int i = 0; i < 4; ++i) {
            const int nn = i * 16 + pt * 4;
            smem[(nn + 0) * 68 + q] = st[i].x;
            smem[(nn + 1) * 68 + q] = st[i].y;
            smem[(nn + 2) * 68 + q] = st[i].z;
            smem[(nn + 3) * 68 + q] = st[i].w;
        }
        __syncthreads();                         // barrier #1 (both halves)

        // ---- fragments from LDS (2 x b128 each) + zsq + bf16(-2x) ----
        bf16x8 afrag[4][2];
        float zsq = 0.f;
        #pragma unroll
        for (int u = 0; u < 4; ++u) {
            #pragma unroll
            for (int s = 0; s < 2; ++s) {
                const float* bse = smem + (u * 16 + n16) * 68 + s * 32 + quad * 8;
                const f32x4 x0 = *(const f32x4*)(bse);
                const f32x4 x1 = *(const f32x4*)(bse + 4);
                #pragma unroll
                for (int j = 0; j < 4; ++j) {
                    zsq = fmaf(x0[j], x0[j], zsq);
                    afrag[u][s][j] = f2bf(-2.f * x0[j]);
                }
                #pragma unroll
                for (int j = 0; j < 4; ++j) {
                    zsq = fmaf(x1[j], x1[j], zsq);
                    afrag[u][s][4 + j] = f2bf(-2.f * x1[j]);
                }
            }
        }

        // ---- 8 tiles back-to-back from registers ----
        f32x4 best[4];
        #pragma unroll
        for (int u = 0; u < 4; ++u) best[u] = (f32x4){1e30f, 1e30f, 1e30f, 1e30f};

        #pragma unroll
        for (int t = 0; t < 8; ++t) {
            const f32x4 ce2 = {e2v[t], e2v[t], e2v[t], e2v[t]};
            #pragma unroll
            for (int u = 0; u < 4; ++u) {        // 4 independent MFMA chains
                f32x4 a = __builtin_amdgcn_mfma_f32_16x16x32_bf16(afrag[u][0], Bv[t][0], ce2, 0, 0, 0);
                a       = __builtin_amdgcn_mfma_f32_16x16x32_bf16(afrag[u][1], Bv[t][1], a,   0, 0, 0);
                #pragma unroll
                for (int r = 0; r < 4; ++r) best[u][r] = fminf(best[u][r], a[r]);
            }
        }

        // ---- min over this wave's 16 cw columns; stash per-item mins ----
        #pragma unroll
        for (int m = 1; m < 16; m <<= 1) {
            #pragma unroll
            for (int u = 0; u < 4; ++u) {
                #pragma unroll
                for (int r = 0; r < 4; ++r)
                    best[u][r] = fminf(best[u][r], __shfl_xor(best[u][r], m, 64));
            }
        }
        if (n16 == 0) {                          // lanes 0,16,32,48
            #pragma unroll
            for (int u = 0; u < 4; ++u) {
                #pragma unroll
                for (int r = 0; r < 4; ++r)      // item = u*16 + quad*4 + r
                    minb[w * 64 + u * 16 + quad * 4 + r] = best[u][r];
            }
        }
        __syncthreads();                         // barrier #2 (both halves)

        // ---- finalize (wave 0 of each half; zsq identical across waves) ----
        if (w == 0) {
            const float mn = fminf(fminf(minb[lane], minb[64 + lane]),
                                   fminf(minb[128 + lane], minb[192 + lane]));
            float val = 1.25f * (mn + zsq);
            #pragma unroll
            for (int off = 32; off > 0; off >>= 1) val += __shfl_down(val, off, 64);
            if (lane == 0) vqPart[vbid] = val;
        }
    }
}

// ---------------------------------------------------------------------------
// reduce: deterministic sum of 2048 CE partials + 1024 VQ partials -> out.
// ---------------------------------------------------------------------------
__global__ __launch_bounds__(256) void reduce_kernel(const float* __restrict__ cePart,
                                                     const float* __restrict__ vqPart,
                                                     float* __restrict__ out)
{
    __shared__ float sm[4];
    const int tid = threadIdx.x;
    float s = 0.f;
    #pragma unroll
    for (int i = 0; i < 8; ++i) s += cePart[tid + i * 256];
    #pragma unroll
    for (int i = 0; i < 4; ++i) s += vqPart[tid + i * 256];
    #pragma unroll
    for (int off = 32; off > 0; off >>= 1) s += __shfl_down(s, off, 64);
    if ((tid & 63) == 0) sm[tid >> 6] = s;
    __syncthreads();
    if (tid == 0) out[0] = (sm[0] + sm[1]) + (sm[2] + sm[3]);
}

extern "C" void kernel_launch(void* const* d_in, const int* in_sizes, int n_in,
                              void* d_out, int out_size, void* d_ws, size_t ws_size,
                              hipStream_t stream) {
    const float* ze  = (const float*)d_in[0];
    const float* emb = (const float*)d_in[1];
    const float* qp  = (const float*)d_in[2];
    const int*   tgt = (const int*)d_in[3];
    float* out = (float*)d_out;

    short* embB   = (short*)d_ws;                                    // 64 KB
    float* e2g    = (float*)((char*)d_ws + 65536);                   // +2 KB
    float* cePart = (float*)((char*)d_ws + 65536 + 2048);            // +8 KB
    float* vqPart = (float*)((char*)d_ws + 65536 + 2048 + 8192);     // +4 KB

    prep_kernel<<<2, 256, 0, stream>>>(emb, embB, e2g);
    mega_kernel<<<1536, 512, 0, stream>>>(ze, qp, tgt, embB, e2g, cePart, vqPart);
    reduce_kernel<<<1, 256, 0, stream>>>(cePart, vqPart, out);
}

// Round 13
// 122.776 us; speedup vs baseline: 1.0468x; 1.0468x over previous
//
#include <hip/hip_runtime.h>
#include <math.h>

#define GAMMA 0.25f
constexpr int B_ = 8, Q_ = 64, N_ = 8192, K_ = 512, C_ = 256;

typedef __attribute__((ext_vector_type(8))) short bf16x8;
typedef __attribute__((ext_vector_type(4))) short short4v;
typedef __attribute__((ext_vector_type(4))) float f32x4;

static __device__ inline short f2bf(float x) {   // RNE float->bf16 bits
    union { float f; unsigned u; } v; v.f = x;
    unsigned r = (v.u + 0x7fffu + ((v.u >> 16) & 1u)) >> 16;
    return (short)r;
}
static __device__ inline float bf2f(short h) {
    union { unsigned u; float f; } v; v.u = ((unsigned)(unsigned short)h) << 16;
    return v.f;
}

// ---------------------------------------------------------------------------
// prep: emb fp32[512][64] -> bf16 embB[512][64] + e2[k]=||bf16(emb_k)||^2 in ws.
// ---------------------------------------------------------------------------
__global__ __launch_bounds__(256) void prep_kernel(const float* __restrict__ emb,
                                                   short* __restrict__ embB,
                                                   float* __restrict__ e2g)
{
    const int r = blockIdx.x * 256 + threadIdx.x;
    if (r >= K_) return;
    const float4* src = (const float4*)(emb + r * Q_);
    short4v* dst = (short4v*)(embB + r * Q_);
    float s = 0.f;
    #pragma unroll
    for (int i = 0; i < 16; ++i) {
        const float4 v = src[i];
        short4v h;
        h[0] = f2bf(v.x); h[1] = f2bf(v.y); h[2] = f2bf(v.z); h[3] = f2bf(v.w);
        dst[i] = h;
        #pragma unroll
        for (int j = 0; j < 4; ++j) { const float a = bf2f(h[j]); s = fmaf(a, a, s); }
    }
    e2g[r] = s;
}

// ---------------------------------------------------------------------------
// mega: R8 configuration, byte-for-byte (best measured: 123.7 us).
// 3072 blocks, role by bid%3 (CE 2048 / VQ 1024 interleaved per CU).
// Session model (R8 vs R11): dur_us is dominated by the harness's ~3x256MiB
// re-poison fills (~124 us); kernel sum 45->97 us moved dur by only 1%.
// Kernel-side levers are exhausted: pattern (R5/R6/R9), structure (R1/R3/R8),
// pipelining (R11), occupancy (R12) all null or regressions; only R7's
// chain-shortening (LDS-staged ze, kept here) ever won.
// ---------------------------------------------------------------------------
__global__ __launch_bounds__(256) void mega_kernel(
    const float* __restrict__ ze, const float* __restrict__ qp,
    const int* __restrict__ tgt, const short* __restrict__ embB,
    const float* __restrict__ e2g,
    float* __restrict__ cePart, float* __restrict__ vqPart)
{
    __shared__ f32x4 sh4[(64 * 68 + 256) / 4];   // 18.4 KB (VQ needs it all)
    const int bid  = blockIdx.x;
    const int tid  = threadIdx.x;
    const int lane = tid & 63;
    const int w    = tid >> 6;

    if (bid % 3 != 0) {
        // ================= CE role (2048 blocks) =================
        const int cbid = bid - bid / 3 - 1;      // 0..2047, dense
        f32x4* parts = sh4;                      // [32]

        const int g    = lane & 7;               // item group (4 items)
        const int c0   = lane >> 3;              // class subgroup (8)

        const int base = cbid * 32;              // 32-aligned => b uniform
        const int b    = base >> 13;
        const int n0   = base & (N_ - 1);
        const float* qpb = qp + (size_t)b * C_ * N_;
        const float* qpn = qpb + n0 + g * 4;
        const int cbase  = w * 64 + c0 * 8;

        float4 v[8];
        #pragma unroll
        for (int j = 0; j < 8; ++j)
            v[j] = *(const float4*)(qpn + (size_t)(cbase + j) * N_);

        float xts[4] = {0.f, 0.f, 0.f, 0.f};
        if ((w == 0) && (lane < 8)) {
            #pragma unroll
            for (int j = 0; j < 4; ++j) {
                const int t = tgt[base + lane * 4 + j];
                xts[j] = qpb[(size_t)t * N_ + n0 + lane * 4 + j];
            }
        }

        f32x4 acc = {0.f, 0.f, 0.f, 0.f};
        #pragma unroll
        for (int j = 0; j < 8; ++j) {
            acc[0] += __expf(v[j].x); acc[1] += __expf(v[j].y);
            acc[2] += __expf(v[j].z); acc[3] += __expf(v[j].w);
        }
        #pragma unroll
        for (int r = 0; r < 4; ++r) {            // reduce over c0 (lane bits 3,4,5)
            acc[r] += __shfl_xor(acc[r], 8, 64);
            acc[r] += __shfl_xor(acc[r], 16, 64);
            acc[r] += __shfl_xor(acc[r], 32, 64);
        }
        if (c0 == 0) parts[w * 8 + g] = acc;
        __syncthreads();

        if (w == 0) {
            float loss = 0.f;
            if (lane < 8) {
                const f32x4 tot = (parts[lane] + parts[8 + lane]) +
                                  (parts[16 + lane] + parts[24 + lane]);
                #pragma unroll
                for (int j = 0; j < 4; ++j) loss += __logf(tot[j]) - xts[j];
            }
            loss += __shfl_down(loss, 4, 64);
            loss += __shfl_down(loss, 2, 64);
            loss += __shfl_down(loss, 1, 64);
            if (lane == 0) cePart[cbid] = loss;
        }
    } else {
        // ================= VQ role (1024 blocks) =================
        const int vbid = bid / 3;                // 0..1023
        float* smem = (float*)sh4;
        float* minb = smem + 64 * 68;

        const int n16  = lane & 15;
        const int quad = lane >> 4;

        const int base = vbid * 64;              // 64-aligned => b uniform
        const int b    = base >> 13;
        const int n0   = base & (N_ - 1);
        const float* zb = ze + (size_t)b * Q_ * N_;

        // ---- issue ze tile loads: thread owns q=tid>>2, quarter pt=tid&3 ----
        const int q  = tid >> 2;
        const int pt = tid & 3;
        const float* zq = zb + (size_t)q * N_ + n0 + pt * 4;
        float4 st[4];
        #pragma unroll
        for (int i = 0; i < 4; ++i)
            st[i] = *(const float4*)(zq + i * 16);

        // ---- issue B tiles + e2 while ze lands (reused data, cached) ----
        const short* bb = embB + (w * 128 + n16) * Q_ + quad * 8;
        bf16x8 Bv[8][2];
        float  e2v[8];
        #pragma unroll
        for (int t = 0; t < 8; ++t) {
            Bv[t][0] = *(const bf16x8*)(bb + t * 16 * Q_);
            Bv[t][1] = *(const bf16x8*)(bb + t * 16 * Q_ + 32);
            e2v[t]   = e2g[w * 128 + t * 16 + n16];
        }

        // ---- write ze to LDS transposed [n][q] ----
        #pragma unroll
        for (int i = 0; i < 4; ++i) {
            const int nn = i * 16 + pt * 4;
            smem[(nn + 0) * 68 + q] = st[i].x;
            smem[(nn + 1) * 68 + q] = st[i].y;
            smem[(nn + 2) * 68 + q] = st[i].z;
            smem[(nn + 3) * 68 + q] = st[i].w;
        }
        __syncthreads();

        // ---- fragments from LDS (2 x b128 each) + zsq + bf16(-2x) ----
        bf16x8 afrag[4][2];
        float zsq = 0.f;
        #pragma unroll
        for (int u = 0; u < 4; ++u) {
            #pragma unroll
            for (int s = 0; s < 2; ++s) {
                const float* bse = smem + (u * 16 + n16) * 68 + s * 32 + quad * 8;
                const f32x4 x0 = *(const f32x4*)(bse);
                const f32x4 x1 = *(const f32x4*)(bse + 4);
                #pragma unroll
                for (int j = 0; j < 4; ++j) {
                    zsq = fmaf(x0[j], x0[j], zsq);
                    afrag[u][s][j] = f2bf(-2.f * x0[j]);
                }
                #pragma unroll
                for (int j = 0; j < 4; ++j) {
                    zsq = fmaf(x1[j], x1[j], zsq);
                    afrag[u][s][4 + j] = f2bf(-2.f * x1[j]);
                }
            }
        }

        // ---- 8 tiles back-to-back from registers ----
        f32x4 best[4];
        #pragma unroll
        for (int u = 0; u < 4; ++u) best[u] = (f32x4){1e30f, 1e30f, 1e30f, 1e30f};

        #pragma unroll
        for (int t = 0; t < 8; ++t) {
            const f32x4 ce2 = {e2v[t], e2v[t], e2v[t], e2v[t]};
            #pragma unroll
            for (int u = 0; u < 4; ++u) {        // 4 independent MFMA chains
                f32x4 a = __builtin_amdgcn_mfma_f32_16x16x32_bf16(afrag[u][0], Bv[t][0], ce2, 0, 0, 0);
                a       = __builtin_amdgcn_mfma_f32_16x16x32_bf16(afrag[u][1], Bv[t][1], a,   0, 0, 0);
                #pragma unroll
                for (int r = 0; r < 4; ++r) best[u][r] = fminf(best[u][r], a[r]);
            }
        }

        // ---- min over this wave's 16 cw columns; stash per-item mins ----
        #pragma unroll
        for (int m = 1; m < 16; m <<= 1) {
            #pragma unroll
            for (int u = 0; u < 4; ++u) {
                #pragma unroll
                for (int r = 0; r < 4; ++r)
                    best[u][r] = fminf(best[u][r], __shfl_xor(best[u][r], m, 64));
            }
        }
        if (n16 == 0) {                          // lanes 0,16,32,48
            #pragma unroll
            for (int u = 0; u < 4; ++u) {
                #pragma unroll
                for (int r = 0; r < 4; ++r)      // item = u*16 + quad*4 + r
                    minb[w * 64 + u * 16 + quad * 4 + r] = best[u][r];
            }
        }
        __syncthreads();

        // ---- finalize (wave 0; zsq identical across waves) ----
        if (w == 0) {
            const float mn = fminf(fminf(minb[lane], minb[64 + lane]),
                                   fminf(minb[128 + lane], minb[192 + lane]));
            float val = 1.25f * (mn + zsq);
            #pragma unroll
            for (int off = 32; off > 0; off >>= 1) val += __shfl_down(val, off, 64);
            if (lane == 0) vqPart[vbid] = val;
        }
    }
}

// ---------------------------------------------------------------------------
// reduce: deterministic sum of 2048 CE partials + 1024 VQ partials -> out.
// ---------------------------------------------------------------------------
__global__ __launch_bounds__(256) void reduce_kernel(const float* __restrict__ cePart,
                                                     const float* __restrict__ vqPart,
                                                     float* __restrict__ out)
{
    __shared__ float sm[4];
    const int tid = threadIdx.x;
    float s = 0.f;
    #pragma unroll
    for (int i = 0; i < 8; ++i) s += cePart[tid + i * 256];
    #pragma unroll
    for (int i = 0; i < 4; ++i) s += vqPart[tid + i * 256];
    #pragma unroll
    for (int off = 32; off > 0; off >>= 1) s += __shfl_down(s, off, 64);
    if ((tid & 63) == 0) sm[tid >> 6] = s;
    __syncthreads();
    if (tid == 0) out[0] = (sm[0] + sm[1]) + (sm[2] + sm[3]);
}

extern "C" void kernel_launch(void* const* d_in, const int* in_sizes, int n_in,
                              void* d_out, int out_size, void* d_ws, size_t ws_size,
                              hipStream_t stream) {
    const float* ze  = (const float*)d_in[0];
    const float* emb = (const float*)d_in[1];
    const float* qp  = (const float*)d_in[2];
    const int*   tgt = (const int*)d_in[3];
    float* out = (float*)d_out;

    short* embB   = (short*)d_ws;                                    // 64 KB
    float* e2g    = (float*)((char*)d_ws + 65536);                   // +2 KB
    float* cePart = (float*)((char*)d_ws + 65536 + 2048);            // +8 KB
    float* vqPart = (float*)((char*)d_ws + 65536 + 2048 + 8192);     // +4 KB

    prep_kernel<<<2, 256, 0, stream>>>(emb, embB, e2g);
    mega_kernel<<<3072, 256, 0, stream>>>(ze, qp, tgt, embB, e2g, cePart, vqPart);
    reduce_kernel<<<1, 256, 0, stream>>>(cePart, vqPart, out);
}